// Round 14
// baseline (261.090 us; speedup 1.0000x reference)
//
#include <hip/hip_runtime.h>
#include <math.h>

typedef _Float16 half_t;
typedef __attribute__((ext_vector_type(8))) _Float16 half8;
typedef __attribute__((ext_vector_type(4))) _Float16 half4;
typedef __attribute__((ext_vector_type(4))) float floatx4;

#define TDIM 36
#define PDIM 161        // 2*80+1 atoms
#define NCOL 50
#define NITER 100       // even (loop unrolled x2)
#define PITER8 50       // power steps on G^8 == 400 on G (proven config)

// FUSED single-GEMM FISTA: x_new = shrink(y + L_inv*(A'.y) + B), A' = -Dt.D
// (161x161 const, fp16 in regs), B = L_inv*Dt.Y (fp32 const per thread).
// One barrier/iter via y double-buffer (BY_Y <-> BY_GA head), loop unrolled x2.
// R8/R13 two-phase had 2 barriers + R round-trip; this removes both.
// Wave map (12 waves): g=wave>>1 owns pt {g,g+6} (pt=11 ghost), h=wave&1 owns
// stripes {2h,2h+1}. Per wave/iter: 12 y-reads, 24 MFMA (hi-only), 4 y-writes.
#define NKA 6
#define GSTR 44
#define SPS 164         // Df (fp32) row stride (dwords); fits Df inside BY_Y

// row strides in BYTES
#define YROW 384        // y [64 cols][192 atoms] half
#define GAR  384        // GA' [192 atoms][192 atoms] half (A-operand layout)
#define DROW 384        // DAH [36 t][192 atoms] half (reconst A-operand)
#define TROW 128        // DT  [176 atoms][64 t] half (GA-GEMM operands)

// XOR swizzle: spread same-column accesses across 8 rows -> 8 distinct 16B slots
#define SWZ(row, byteoff) ((byteoff) ^ (((row) & 7) << 4))

// ---- byte-offset LDS map: 149,032 B (1 block/CU) ----
#define BY_Y    0                      // 24,576  (y buffer 0; Df alias 23,616)
#define BY_GA   24576                  // 73,728  (GA'; head 24,576 = y buffer 1;
                                       //          G2 alias +0, G4 alias +6336 in setup)
#define BY_DAH  98304                  // 13,824
#define BY_DT   112128                 // 22,528
#define BY_LRTH 134656                 //  1,288
#define BY_SC   135944                 //     16
#define BY_TTF  135960                 //    400
#define BY_GS   136360                 //  6,336
#define BY_G8   142696                 //  6,336  (dedicated: power iter reads while
                                       //          GA GEMM overwrites G2/G4 aliases)
#define LDS_TOTAL 149032

#define MFMA16 __builtin_amdgcn_mfma_f32_16x16x32_f16

__global__ __launch_bounds__(768, 3)
void dan_kernel(const float* __restrict__ xin, const float* __restrict__ rho,
                const float* __restrict__ theta, float* __restrict__ outC,
                float* __restrict__ outDic, float* __restrict__ outR)
{
  extern __shared__ char smc[];
  float*  sc   = (float*)(smc + BY_SC);
  float*  ttfT = (float*)(smc + BY_TTF);
  float*  Gs   = (float*)(smc + BY_GS);
  float*  G2a  = (float*)(smc + BY_GA);            // setup alias
  float*  G4a  = (float*)(smc + BY_GA + 6336);     // setup alias
  float*  G8p  = (float*)(smc + BY_G8);
  float*  Df   = (float*)(smc + BY_Y);             // setup alias (23,616 B)
  float*  lrth = (float*)(smc + BY_LRTH);

  const int tid = threadIdx.x;
  const int b = blockIdx.x;
  const int wave = tid >> 6, lane = tid & 63;
  const int q = lane >> 4, ln = lane & 15;

  // ---- A. zero all LDS (pads must be 0)
  {
    unsigned int* z = (unsigned int*)smc;
    for (int i = tid; i < LDS_TOTAL / 4; i += 768) z[i] = 0u;
  }
  __syncthreads();

  // ---- B0. per-atom lr/th
  if (tid >= 1 && tid < PDIM) {
    const bool is_sin = tid > 80;
    const int n = is_sin ? (tid - 81) : (tid - 1);
    lrth[tid]       = logf(0.001f + 1.149f / (1.0f + expf(-rho[n])));
    lrth[161 + tid] = 3.14159265358979f / (1.0f + expf(-theta[n]));
  }
  __syncthreads();

  // ---- B1. raw dictionary (SPS=164; pad cols 161..163 stay zero)
  for (int i = tid; i < TDIM * PDIM; i += 768) {
    const int t = i / PDIM, p = i - t * PDIM;
    float val;
    if (p == 0) {
      val = 1.0f;
    } else {
      const float ft = (float)t;
      const float e = expf(ft * lrth[p]);
      const float ang = ft * lrth[161 + p];
      val = e * (p > 80 ? sinf(ang) : cosf(ang));
    }
    Df[t * SPS + p] = val;
  }
  __syncthreads();

  // ---- B2. column-normalize (atoms 1..160)
  if (tid >= 1 && tid < PDIM) {
    float s2 = 0.0f;
    for (int t = 0; t < TDIM; ++t) {
      const float v = Df[t * SPS + tid];
      s2 += v * v;
    }
    const float inv = 1.0f / sqrtf(s2);
    for (int t = 0; t < TDIM; ++t) Df[t * SPS + tid] *= inv;
  }
  __syncthreads();

  // ---- C. Gram36 -> Gs ; stage DT (GA operands) + DAH (reconst) ; dic out
  if (tid < 666) {                      // 666 = 36*37/2
    int i = 0, rem = tid;
    while (rem >= TDIM - i) { rem -= TDIM - i; ++i; }
    const int j = i + rem;
    const float4* ri = (const float4*)(Df + i * SPS);
    const float4* rj = (const float4*)(Df + j * SPS);
    float a = 0.0f;
    for (int k = 0; k < SPS / 4; ++k) {
      const float4 x = ri[k], y = rj[k];
      a += x.x * y.x + x.y * y.y + x.z * y.z + x.w * y.w;
    }
    Gs[i * GSTR + j] = a;
    Gs[j * GSTR + i] = a;
  }
  for (int i = tid; i < TDIM * PDIM; i += 768) {
    const int t = i / PDIM, p = i - t * PDIM;
    const float v = Df[t * SPS + p];
    const half_t hh = (half_t)v;
    *(half_t*)(smc + BY_DT + p * TROW + SWZ(p, t * 2)) = hh;
    *(half_t*)(smc + BY_DAH + t * DROW + SWZ(t, p * 2)) = hh;
    if (b == 0) outDic[i] = v;
  }
  __syncthreads();

  // ---- C2. G2 = Gs^2 (into GA alias; pads zero from memset)
  if (tid < 666) {
    int i = 0, rem = tid;
    while (rem >= TDIM - i) { rem -= TDIM - i; ++i; }
    const int j = i + rem;
    const float4* ri = (const float4*)(Gs + i * GSTR);
    const float4* rj = (const float4*)(Gs + j * GSTR);
    float a = 0.0f;
    #pragma unroll
    for (int k = 0; k < GSTR / 4; ++k) {
      const float4 x = ri[k], y = rj[k];
      a += x.x * y.x + x.y * y.y + x.z * y.z + x.w * y.w;
    }
    G2a[i * GSTR + j] = a;
    G2a[j * GSTR + i] = a;
  }
  __syncthreads();
  // ---- C3. G4 = G2^2
  if (tid < 666) {
    int i = 0, rem = tid;
    while (rem >= TDIM - i) { rem -= TDIM - i; ++i; }
    const int j = i + rem;
    const float4* ri = (const float4*)(G2a + i * GSTR);
    const float4* rj = (const float4*)(G2a + j * GSTR);
    float a = 0.0f;
    #pragma unroll
    for (int k = 0; k < GSTR / 4; ++k) {
      const float4 x = ri[k], y = rj[k];
      a += x.x * y.x + x.y * y.y + x.z * y.z + x.w * y.w;
    }
    G4a[i * GSTR + j] = a;
    G4a[j * GSTR + i] = a;
  }
  __syncthreads();
  // ---- C4. G8 = G4^2 -> DEDICATED region (survives GA GEMM)
  if (tid < 666) {
    int i = 0, rem = tid;
    while (rem >= TDIM - i) { rem -= TDIM - i; ++i; }
    const int j = i + rem;
    const float4* ri = (const float4*)(G4a + i * GSTR);
    const float4* rj = (const float4*)(G4a + j * GSTR);
    float a = 0.0f;
    #pragma unroll
    for (int k = 0; k < GSTR / 4; ++k) {
      const float4 x = ri[k], y = rj[k];
      a += x.x * y.x + x.y * y.y + x.z * y.z + x.w * y.w;
    }
    G8p[i * GSTR + j] = a;
    G8p[j * GSTR + i] = a;
  }
  __syncthreads();

  // ---- D. fork: wave0 power-iters on G8; waves 1..11 build GA' = -Dt.D (fp16)
  if (wave == 0) {
    float g8r[36];
    #pragma unroll
    for (int j = 0; j < 36; ++j) g8r[j] = (lane < 36) ? G8p[lane * GSTR + j] : 0.0f;
    float v = (lane < 36) ? 1.0f : 0.0f;
    for (int it = 0; it < PITER8; ++it) {
      const int vi = __float_as_int(v);
      float w0 = 0.0f, w1 = 0.0f, w2 = 0.0f, w3 = 0.0f;
      #pragma unroll
      for (int j = 0; j < 36; j += 4) {
        w0 = fmaf(g8r[j],     __int_as_float(__builtin_amdgcn_readlane(vi, j)),     w0);
        w1 = fmaf(g8r[j + 1], __int_as_float(__builtin_amdgcn_readlane(vi, j + 1)), w1);
        w2 = fmaf(g8r[j + 2], __int_as_float(__builtin_amdgcn_readlane(vi, j + 2)), w2);
        w3 = fmaf(g8r[j + 3], __int_as_float(__builtin_amdgcn_readlane(vi, j + 3)), w3);
      }
      float w = (w0 + w1) + (w2 + w3);
      float s = w * w;
      #pragma unroll
      for (int off = 32; off > 0; off >>= 1) s += __shfl_xor(s, off, 64);
      v = w * rsqrtf(s);
    }
    // Rayleigh on ORIGINAL G (v is unit)
    const int vi = __float_as_int(v);
    float w0 = 0.0f, w1 = 0.0f;
    #pragma unroll
    for (int j = 0; j < 36; j += 2) {
      const float gi0 = (lane < 36) ? Gs[lane * GSTR + j]     : 0.0f;
      const float gi1 = (lane < 36) ? Gs[lane * GSTR + j + 1] : 0.0f;
      w0 = fmaf(gi0, __int_as_float(__builtin_amdgcn_readlane(vi, j)),     w0);
      w1 = fmaf(gi1, __int_as_float(__builtin_amdgcn_readlane(vi, j + 1)), w1);
    }
    float num = v * (w0 + w1);
    #pragma unroll
    for (int off = 32; off > 0; off >>= 1) num += __shfl_xor(num, off, 64);
    if (lane == 0) {
      sc[0] = 1.0f / num;        // L_inv
      sc[1] = 0.1f / num;        // thr = lam_f * L_inv
    }
  } else {
    // zero logical cols 176..191 of GA rows 0..32 (stale G2/G4 alias bytes)
    for (int i = tid - 64; i < 33 * 16; i += 704) {
      const int row = i >> 4, hh = i & 15;
      *(half_t*)(smc + BY_GA + row * GAR + SWZ(row, (176 + hh) * 2)) = (half_t)0.0f;
    }
    // GA' tiles: 121 tiles over 11 waves; C[i][j] = -dot(d_i, d_j)
    for (int tile = wave - 1; tile < 121; tile += 11) {
      const int pti = tile / 11, ntj = tile - 11 * (tile / 11);
      const int rowA = 16 * pti + ln, rowB = 16 * ntj + ln;
      const char* da = smc + BY_DT + rowA * TROW;
      const char* db = smc + BY_DT + rowB * TROW;
      const half8 a0 = *(const half8*)(da + SWZ(rowA, 16 * q));
      const half8 a1 = *(const half8*)(da + SWZ(rowA, 64 + 16 * q));
      const half8 b0 = *(const half8*)(db + SWZ(rowB, 16 * q));
      const half8 b1 = *(const half8*)(db + SWZ(rowB, 64 + 16 * q));
      floatx4 acc = {0.f, 0.f, 0.f, 0.f};
      acc = MFMA16(a0, b0, acc, 0, 0, 0);
      acc = MFMA16(a1, b1, acc, 0, 0, 0);
      const int gcol = 16 * ntj + ln;
      #pragma unroll
      for (int r = 0; r < 4; ++r) {
        const int gi = 16 * pti + 4 * q + r;
        *(half_t*)(smc + BY_GA + gi * GAR + SWZ(gi, gcol * 2)) = (half_t)(-acc[r]);
      }
    }
    if (tid == 64) {
      // data-independent momentum table (exact f32 ops of the reference recurrence)
      float t = 1.0f;
      for (int it = 0; it < NITER; ++it) {
        const float tn = 0.5f * (1.0f + sqrtf(1.0f + 4.0f * t * t));
        ttfT[it] = (t - 1.0f) / tn;
        t = tn;
      }
    }
  }
  __syncthreads();
  const float L_inv = sc[0];
  const float thr = sc[1];

  // ---- E. A'-fragments (48 VGPR) + B (fp32, exact) ; then kill Df, zero y bufs
  const int g = wave >> 1;              // pt in {g, g+6} (pt=11 ghost: GA rows zero)
  const int h = wave & 1;               // stripes {2h, 2h+1}

  half8 GF[2][NKA];
  #pragma unroll
  for (int k = 0; k < 2; ++k) {
    const int row = 16 * (g + 6 * k) + ln;          // up to 191; rows>=176 zero
    const char* ga = smc + BY_GA + row * GAR;
    #pragma unroll
    for (int ks = 0; ks < NKA; ++ks)
      GF[k][ks] = *(const half8*)(ga + SWZ(row, (32 * ks + 8 * q) * 2));
  }
  float Bc[2][2][4];
  {
    const float* xb = xin + b * TDIM * NCOL;
    #pragma unroll
    for (int k = 0; k < 2; ++k) {
      #pragma unroll
      for (int s = 0; s < 2; ++s) {
        const int cS = 16 * (2 * h + s) + ln;
        #pragma unroll
        for (int r = 0; r < 4; ++r) {
          const int p = 16 * (g + 6 * k) + 4 * q + r;
          float acc = 0.0f;
          if (p < PDIM && cS < NCOL) {
            for (int t = 0; t < TDIM; ++t)
              acc = fmaf(Df[t * SPS + p], xb[t * NCOL + cS], acc);
          }
          Bc[k][s][r] = L_inv * acc;
        }
      }
    }
  }
  __syncthreads();                      // Df reads done before y-zero
  {
    unsigned int* z = (unsigned int*)smc;
    for (int i = tid; i < 24576 / 4; i += 768) {
      z[i] = 0u;                        // y buffer 0 (kills Df alias)
      z[i + 24576 / 4] = 0u;            // y buffer 1 (GA head; GA now dead)
    }
  }
  __syncthreads();

  // ---- hoisted loop-invariant LDS addresses
  const char* yrd[2][NKA];
  char* ywr[2][2];                      // [k][s]
  #pragma unroll
  for (int s = 0; s < 2; ++s) {
    const int cS = 16 * (2 * h + s) + ln;
    #pragma unroll
    for (int ks = 0; ks < NKA; ++ks)
      yrd[s][ks] = smc + BY_Y + cS * YROW + SWZ(cS, (32 * ks + 8 * q) * 2);
    #pragma unroll
    for (int k = 0; k < 2; ++k) {
      const int p0 = 16 * (g + 6 * k) + 4 * q;
      ywr[k][s] = smc + BY_Y + cS * YROW + SWZ(cS, p0 * 2);
    }
  }

  float xR[2][2][4], yR[2][2][4];       // [pt-idx][stripe][r]
  #pragma unroll
  for (int k = 0; k < 2; ++k)
    #pragma unroll
    for (int s = 0; s < 2; ++s)
      #pragma unroll
      for (int r = 0; r < 4; ++r) { xR[k][s][r] = 0.0f; yR[k][s][r] = 0.0f; }

  // ---- F. fused FISTA loop: 1 GEMM + 1 barrier per iter (y double-buffered)
#define ITER_BODY(RD, WR, ITIDX)                                               \
  do {                                                                         \
    const float ttf = ttfT[ITIDX];                                             \
    _Pragma("unroll")                                                          \
    for (int s = 0; s < 2; ++s) {                                              \
      half8 yb[NKA];                                                           \
      _Pragma("unroll")                                                        \
      for (int ks = 0; ks < NKA; ++ks)                                         \
        yb[ks] = *(const half8*)(yrd[s][ks] + (RD));                           \
      _Pragma("unroll")                                                        \
      for (int k = 0; k < 2; ++k) {                                            \
        floatx4 a = {0.f, 0.f, 0.f, 0.f};                                      \
        _Pragma("unroll")                                                      \
        for (int ks = 0; ks < NKA; ++ks)                                       \
          a = MFMA16(GF[k][ks], yb[ks], a, 0, 0, 0);                           \
        half4 hv;                                                              \
        _Pragma("unroll")                                                      \
        for (int r = 0; r < 4; ++r) {                                          \
          const float w = yR[k][s][r] + fmaf(L_inv, a[r], Bc[k][s][r]);        \
          const float cl = fminf(fmaxf(w, -thr), thr);                         \
          const float xn = w - cl;                                             \
          const float yn = xn + ttf * (xn - xR[k][s][r]);                      \
          xR[k][s][r] = xn;                                                    \
          yR[k][s][r] = yn;                                                    \
          hv[r] = (half_t)yn;                                                  \
        }                                                                      \
        *(half4*)(ywr[k][s] + (WR)) = hv;                                      \
      }                                                                        \
    }                                                                          \
  } while (0)

  for (int it = 0; it < NITER; it += 2) {
    ITER_BODY(0, 24576, it);            // read buf0, write buf1
    __syncthreads();
    ITER_BODY(24576, 0, it + 1);        // read buf1, write buf0
    __syncthreads();
  }

  // ---- G. outputs: C = x_fin
  float* Cb = outC + b * PDIM * NCOL;
  #pragma unroll
  for (int k = 0; k < 2; ++k) {
    const int pt = g + 6 * k;
    #pragma unroll
    for (int s = 0; s < 2; ++s) {
      const int cS = 16 * (2 * h + s) + ln;
      if (cS < NCOL) {
        #pragma unroll
        for (int r = 0; r < 4; ++r) {
          const int p = 16 * pt + 4 * q + r;
          if (p < PDIM) Cb[p * NCOL + cS] = xR[k][s][r];
        }
      }
    }
  }
  // reconst = D @ C : stage x into buf0 (fp16), one hi-only GEMM from DAH
  #pragma unroll
  for (int k = 0; k < 2; ++k) {
    #pragma unroll
    for (int s = 0; s < 2; ++s) {
      half4 hv;
      #pragma unroll
      for (int r = 0; r < 4; ++r) hv[r] = (half_t)xR[k][s][r];
      *(half4*)(ywr[k][s]) = hv;
    }
  }
  __syncthreads();
  {
    const int mtA = wave >> 2, ntA = wave & 3;     // 3 mt x 4 nt
    const int rowD = 16 * mtA + ln;                // 0..47 (>=36 -> zero frag)
    const int n0 = 16 * ntA + ln;
    const half8 zz = {0, 0, 0, 0, 0, 0, 0, 0};
    floatx4 a = {0.f, 0.f, 0.f, 0.f};
    #pragma unroll
    for (int ks = 0; ks < NKA; ++ks) {
      const half8 dh_ = (rowD < TDIM)
        ? *(const half8*)(smc + BY_DAH + rowD * DROW + SWZ(rowD, (32 * ks + 8 * q) * 2))
        : zz;
      const half8 yb = *(const half8*)(smc + BY_Y + n0 * YROW + SWZ(n0, (32 * ks + 8 * q) * 2));
      a = MFMA16(dh_, yb, a, 0, 0, 0);
    }
    float* Rb = outR + b * TDIM * NCOL;
    if (n0 < NCOL) {
      const int t0 = 16 * mtA + 4 * q;
      #pragma unroll
      for (int r = 0; r < 4; ++r) {
        const int t = t0 + r;
        if (t < TDIM) Rb[t * NCOL + n0] = a[r];
      }
    }
  }
}

// ---------------- launch --------------------------------------------------------------

extern "C" void kernel_launch(void* const* d_in, const int* in_sizes, int n_in,
                              void* d_out, int out_size, void* d_ws, size_t ws_size,
                              hipStream_t stream) {
  const float* x     = (const float*)d_in[0];   // (256, 36, 50)
  const float* rho   = (const float*)d_in[1];   // (80,)
  const float* theta = (const float*)d_in[2];   // (80,)

  float* out    = (float*)d_out;
  float* outC   = out;                              // 256*161*50
  float* outDic = out + 256 * PDIM * NCOL;          // 36*161
  float* outR   = outDic + TDIM * PDIM;             // 256*36*50

  hipLaunchKernelGGL(dan_kernel, dim3(256), dim3(768), LDS_TOTAL, stream,
                     x, rho, theta, outC, outDic, outR);
}

// Round 15
// 251.344 us; speedup vs baseline: 1.0388x; 1.0388x over previous
//
#include <hip/hip_runtime.h>
#include <math.h>

typedef _Float16 half_t;
typedef __attribute__((ext_vector_type(8))) _Float16 half8;
typedef __attribute__((ext_vector_type(4))) _Float16 half4;
typedef __attribute__((ext_vector_type(4))) float floatx4;

#define TDIM 36
#define PDIM 161        // 2*80+1 atoms
#define NCOL 50
#define NITER 100       // even (loop unrolled x2)
#define PITER8 50       // power steps on G^8 == 400 on G (proven config)

// FUSED single-GEMM FISTA: x_new = shrink(y + L_inv*(A'.y) + B), A' = -Dt.D
// (161x161 const, fp16 in regs), B = L_inv*Dt.Y (fp32 const per thread).
// One barrier/iter via y double-buffer (BY_Y <-> BY_GA head), loop unrolled x2.
// R14 LESSON: loading GF (48 VGPR) BEFORE the long Bc reduction spilled GF
// across it (112 MB scratch traffic, 223 us). This round: Bc FIRST, GF after.
// Wave map (12 waves): g=wave>>1 owns pt {g,g+6} (pt=11 ghost), h=wave&1 owns
// stripes {2h,2h+1}. Per wave/iter: 12 y-reads, 24 MFMA (hi-only), 4 y-writes.
#define NKA 6
#define GSTR 44
#define SPS 164         // Df (fp32) row stride (dwords); fits Df inside BY_Y

// row strides in BYTES
#define YROW 384        // y [64 cols][192 atoms] half
#define GAR  384        // GA' [192 atoms][192 atoms] half (A-operand layout)
#define DROW 384        // DAH [36 t][192 atoms] half (reconst A-operand)
#define TROW 128        // DT  [176 atoms][64 t] half (GA-GEMM operands)

// XOR swizzle: spread same-column accesses across 8 rows -> 8 distinct 16B slots
#define SWZ(row, byteoff) ((byteoff) ^ (((row) & 7) << 4))

// ---- byte-offset LDS map: 149,032 B (1 block/CU) ----
#define BY_Y    0                      // 24,576  (y buffer 0; Df alias 23,616)
#define BY_GA   24576                  // 73,728  (GA'; head 24,576 = y buffer 1;
                                       //          G2 alias +0, G4 alias +6336 in setup)
#define BY_DAH  98304                  // 13,824
#define BY_DT   112128                 // 22,528
#define BY_LRTH 134656                 //  1,288
#define BY_SC   135944                 //     16
#define BY_TTF  135960                 //    400
#define BY_GS   136360                 //  6,336
#define BY_G8   142696                 //  6,336  (dedicated: power iter reads while
                                       //          GA GEMM overwrites G2/G4 aliases)
#define LDS_TOTAL 149032

#define MFMA16 __builtin_amdgcn_mfma_f32_16x16x32_f16

__global__ __launch_bounds__(768, 3)
void dan_kernel(const float* __restrict__ xin, const float* __restrict__ rho,
                const float* __restrict__ theta, float* __restrict__ outC,
                float* __restrict__ outDic, float* __restrict__ outR)
{
  extern __shared__ char smc[];
  float*  sc   = (float*)(smc + BY_SC);
  float*  ttfT = (float*)(smc + BY_TTF);
  float*  Gs   = (float*)(smc + BY_GS);
  float*  G2a  = (float*)(smc + BY_GA);            // setup alias
  float*  G4a  = (float*)(smc + BY_GA + 6336);     // setup alias
  float*  G8p  = (float*)(smc + BY_G8);
  float*  Df   = (float*)(smc + BY_Y);             // setup alias (23,616 B)
  float*  lrth = (float*)(smc + BY_LRTH);

  const int tid = threadIdx.x;
  const int b = blockIdx.x;
  const int wave = tid >> 6, lane = tid & 63;
  const int q = lane >> 4, ln = lane & 15;

  // ---- A. zero all LDS (pads must be 0)
  {
    unsigned int* z = (unsigned int*)smc;
    for (int i = tid; i < LDS_TOTAL / 4; i += 768) z[i] = 0u;
  }
  __syncthreads();

  // ---- B0. per-atom lr/th
  if (tid >= 1 && tid < PDIM) {
    const bool is_sin = tid > 80;
    const int n = is_sin ? (tid - 81) : (tid - 1);
    lrth[tid]       = logf(0.001f + 1.149f / (1.0f + expf(-rho[n])));
    lrth[161 + tid] = 3.14159265358979f / (1.0f + expf(-theta[n]));
  }
  __syncthreads();

  // ---- B1. raw dictionary (SPS=164; pad cols 161..163 stay zero)
  for (int i = tid; i < TDIM * PDIM; i += 768) {
    const int t = i / PDIM, p = i - t * PDIM;
    float val;
    if (p == 0) {
      val = 1.0f;
    } else {
      const float ft = (float)t;
      const float e = expf(ft * lrth[p]);
      const float ang = ft * lrth[161 + p];
      val = e * (p > 80 ? sinf(ang) : cosf(ang));
    }
    Df[t * SPS + p] = val;
  }
  __syncthreads();

  // ---- B2. column-normalize (atoms 1..160)
  if (tid >= 1 && tid < PDIM) {
    float s2 = 0.0f;
    for (int t = 0; t < TDIM; ++t) {
      const float v = Df[t * SPS + tid];
      s2 += v * v;
    }
    const float inv = 1.0f / sqrtf(s2);
    for (int t = 0; t < TDIM; ++t) Df[t * SPS + tid] *= inv;
  }
  __syncthreads();

  // ---- C. Gram36 -> Gs ; stage DT (GA operands) + DAH (reconst) ; dic out
  if (tid < 666) {                      // 666 = 36*37/2
    int i = 0, rem = tid;
    while (rem >= TDIM - i) { rem -= TDIM - i; ++i; }
    const int j = i + rem;
    const float4* ri = (const float4*)(Df + i * SPS);
    const float4* rj = (const float4*)(Df + j * SPS);
    float a = 0.0f;
    for (int k = 0; k < SPS / 4; ++k) {
      const float4 x = ri[k], y = rj[k];
      a += x.x * y.x + x.y * y.y + x.z * y.z + x.w * y.w;
    }
    Gs[i * GSTR + j] = a;
    Gs[j * GSTR + i] = a;
  }
  for (int i = tid; i < TDIM * PDIM; i += 768) {
    const int t = i / PDIM, p = i - t * PDIM;
    const float v = Df[t * SPS + p];
    const half_t hh = (half_t)v;
    *(half_t*)(smc + BY_DT + p * TROW + SWZ(p, t * 2)) = hh;
    *(half_t*)(smc + BY_DAH + t * DROW + SWZ(t, p * 2)) = hh;
    if (b == 0) outDic[i] = v;
  }
  __syncthreads();

  // ---- C2. G2 = Gs^2 (into GA alias; pads zero from memset)
  if (tid < 666) {
    int i = 0, rem = tid;
    while (rem >= TDIM - i) { rem -= TDIM - i; ++i; }
    const int j = i + rem;
    const float4* ri = (const float4*)(Gs + i * GSTR);
    const float4* rj = (const float4*)(Gs + j * GSTR);
    float a = 0.0f;
    #pragma unroll
    for (int k = 0; k < GSTR / 4; ++k) {
      const float4 x = ri[k], y = rj[k];
      a += x.x * y.x + x.y * y.y + x.z * y.z + x.w * y.w;
    }
    G2a[i * GSTR + j] = a;
    G2a[j * GSTR + i] = a;
  }
  __syncthreads();
  // ---- C3. G4 = G2^2
  if (tid < 666) {
    int i = 0, rem = tid;
    while (rem >= TDIM - i) { rem -= TDIM - i; ++i; }
    const int j = i + rem;
    const float4* ri = (const float4*)(G2a + i * GSTR);
    const float4* rj = (const float4*)(G2a + j * GSTR);
    float a = 0.0f;
    #pragma unroll
    for (int k = 0; k < GSTR / 4; ++k) {
      const float4 x = ri[k], y = rj[k];
      a += x.x * y.x + x.y * y.y + x.z * y.z + x.w * y.w;
    }
    G4a[i * GSTR + j] = a;
    G4a[j * GSTR + i] = a;
  }
  __syncthreads();
  // ---- C4. G8 = G4^2 -> DEDICATED region (survives GA GEMM)
  if (tid < 666) {
    int i = 0, rem = tid;
    while (rem >= TDIM - i) { rem -= TDIM - i; ++i; }
    const int j = i + rem;
    const float4* ri = (const float4*)(G4a + i * GSTR);
    const float4* rj = (const float4*)(G4a + j * GSTR);
    float a = 0.0f;
    #pragma unroll
    for (int k = 0; k < GSTR / 4; ++k) {
      const float4 x = ri[k], y = rj[k];
      a += x.x * y.x + x.y * y.y + x.z * y.z + x.w * y.w;
    }
    G8p[i * GSTR + j] = a;
    G8p[j * GSTR + i] = a;
  }
  __syncthreads();

  // ---- D. fork: wave0 power-iters on G8; waves 1..11 build GA' = -Dt.D (fp16)
  if (wave == 0) {
    float g8r[36];
    #pragma unroll
    for (int j = 0; j < 36; ++j) g8r[j] = (lane < 36) ? G8p[lane * GSTR + j] : 0.0f;
    float v = (lane < 36) ? 1.0f : 0.0f;
    for (int it = 0; it < PITER8; ++it) {
      const int vi = __float_as_int(v);
      float w0 = 0.0f, w1 = 0.0f, w2 = 0.0f, w3 = 0.0f;
      #pragma unroll
      for (int j = 0; j < 36; j += 4) {
        w0 = fmaf(g8r[j],     __int_as_float(__builtin_amdgcn_readlane(vi, j)),     w0);
        w1 = fmaf(g8r[j + 1], __int_as_float(__builtin_amdgcn_readlane(vi, j + 1)), w1);
        w2 = fmaf(g8r[j + 2], __int_as_float(__builtin_amdgcn_readlane(vi, j + 2)), w2);
        w3 = fmaf(g8r[j + 3], __int_as_float(__builtin_amdgcn_readlane(vi, j + 3)), w3);
      }
      float w = (w0 + w1) + (w2 + w3);
      float s = w * w;
      #pragma unroll
      for (int off = 32; off > 0; off >>= 1) s += __shfl_xor(s, off, 64);
      v = w * rsqrtf(s);
    }
    // Rayleigh on ORIGINAL G (v is unit)
    const int vi = __float_as_int(v);
    float w0 = 0.0f, w1 = 0.0f;
    #pragma unroll
    for (int j = 0; j < 36; j += 2) {
      const float gi0 = (lane < 36) ? Gs[lane * GSTR + j]     : 0.0f;
      const float gi1 = (lane < 36) ? Gs[lane * GSTR + j + 1] : 0.0f;
      w0 = fmaf(gi0, __int_as_float(__builtin_amdgcn_readlane(vi, j)),     w0);
      w1 = fmaf(gi1, __int_as_float(__builtin_amdgcn_readlane(vi, j + 1)), w1);
    }
    float num = v * (w0 + w1);
    #pragma unroll
    for (int off = 32; off > 0; off >>= 1) num += __shfl_xor(num, off, 64);
    if (lane == 0) {
      sc[0] = 1.0f / num;        // L_inv
      sc[1] = 0.1f / num;        // thr = lam_f * L_inv
    }
  } else {
    // zero logical cols 176..191 of GA rows 0..32 (stale G2/G4 alias bytes)
    for (int i = tid - 64; i < 33 * 16; i += 704) {
      const int row = i >> 4, hh = i & 15;
      *(half_t*)(smc + BY_GA + row * GAR + SWZ(row, (176 + hh) * 2)) = (half_t)0.0f;
    }
    // GA' tiles: 121 tiles over 11 waves; C[i][j] = -dot(d_i, d_j)
    for (int tile = wave - 1; tile < 121; tile += 11) {
      const int pti = tile / 11, ntj = tile - 11 * (tile / 11);
      const int rowA = 16 * pti + ln, rowB = 16 * ntj + ln;
      const char* da = smc + BY_DT + rowA * TROW;
      const char* db = smc + BY_DT + rowB * TROW;
      const half8 a0 = *(const half8*)(da + SWZ(rowA, 16 * q));
      const half8 a1 = *(const half8*)(da + SWZ(rowA, 64 + 16 * q));
      const half8 b0 = *(const half8*)(db + SWZ(rowB, 16 * q));
      const half8 b1 = *(const half8*)(db + SWZ(rowB, 64 + 16 * q));
      floatx4 acc = {0.f, 0.f, 0.f, 0.f};
      acc = MFMA16(a0, b0, acc, 0, 0, 0);
      acc = MFMA16(a1, b1, acc, 0, 0, 0);
      const int gcol = 16 * ntj + ln;
      #pragma unroll
      for (int r = 0; r < 4; ++r) {
        const int gi = 16 * pti + 4 * q + r;
        *(half_t*)(smc + BY_GA + gi * GAR + SWZ(gi, gcol * 2)) = (half_t)(-acc[r]);
      }
    }
    if (tid == 64) {
      // data-independent momentum table (exact f32 ops of the reference recurrence)
      float t = 1.0f;
      for (int it = 0; it < NITER; ++it) {
        const float tn = 0.5f * (1.0f + sqrtf(1.0f + 4.0f * t * t));
        ttfT[it] = (t - 1.0f) / tn;
        t = tn;
      }
    }
  }
  __syncthreads();
  const float L_inv = sc[0];
  const float thr = sc[1];

  // ---- E. B FIRST (fp32, low reg pressure), THEN A'-fragments (48 VGPR).
  // R14 had GF loaded before this reduction -> GF spilled across it.
  const int g = wave >> 1;              // pt in {g, g+6} (pt=11 ghost: GA rows zero)
  const int h = wave & 1;               // stripes {2h, 2h+1}

  float Bc[2][2][4];
  {
    const float* xb = xin + b * TDIM * NCOL;
    #pragma unroll
    for (int k = 0; k < 2; ++k) {
      #pragma unroll
      for (int s = 0; s < 2; ++s) {
        const int cS = 16 * (2 * h + s) + ln;
        #pragma unroll
        for (int r = 0; r < 4; ++r) {
          const int p = 16 * (g + 6 * k) + 4 * q + r;
          float acc = 0.0f;
          if (p < PDIM && cS < NCOL) {
            for (int t = 0; t < TDIM; ++t)
              acc = fmaf(Df[t * SPS + p], xb[t * NCOL + cS], acc);
          }
          Bc[k][s][r] = L_inv * acc;
        }
      }
    }
  }
  half8 GF[2][NKA];
  #pragma unroll
  for (int k = 0; k < 2; ++k) {
    const int row = 16 * (g + 6 * k) + ln;          // up to 191; rows>=176 zero
    const char* ga = smc + BY_GA + row * GAR;
    #pragma unroll
    for (int ks = 0; ks < NKA; ++ks)
      GF[k][ks] = *(const half8*)(ga + SWZ(row, (32 * ks + 8 * q) * 2));
  }
  __syncthreads();                      // Df/GA reads done before y-zero
  {
    unsigned int* z = (unsigned int*)smc;
    for (int i = tid; i < 24576 / 4; i += 768) {
      z[i] = 0u;                        // y buffer 0 (kills Df alias)
      z[i + 24576 / 4] = 0u;            // y buffer 1 (GA head; GA now dead)
    }
  }
  __syncthreads();

  // ---- hoisted loop-invariant LDS addresses
  const char* yrd[2][NKA];
  char* ywr[2][2];                      // [k][s]
  #pragma unroll
  for (int s = 0; s < 2; ++s) {
    const int cS = 16 * (2 * h + s) + ln;
    #pragma unroll
    for (int ks = 0; ks < NKA; ++ks)
      yrd[s][ks] = smc + BY_Y + cS * YROW + SWZ(cS, (32 * ks + 8 * q) * 2);
    #pragma unroll
    for (int k = 0; k < 2; ++k) {
      const int p0 = 16 * (g + 6 * k) + 4 * q;
      ywr[k][s] = smc + BY_Y + cS * YROW + SWZ(cS, p0 * 2);
    }
  }

  float xR[2][2][4], yR[2][2][4];       // [pt-idx][stripe][r]
  #pragma unroll
  for (int k = 0; k < 2; ++k)
    #pragma unroll
    for (int s = 0; s < 2; ++s)
      #pragma unroll
      for (int r = 0; r < 4; ++r) { xR[k][s][r] = 0.0f; yR[k][s][r] = 0.0f; }

  // ---- F. fused FISTA loop: 1 GEMM + 1 barrier per iter (y double-buffered)
#define ITER_BODY(RD, WR, ITIDX)                                               \
  do {                                                                         \
    const float ttf = ttfT[ITIDX];                                             \
    _Pragma("unroll")                                                          \
    for (int s = 0; s < 2; ++s) {                                              \
      half8 yb[NKA];                                                           \
      _Pragma("unroll")                                                        \
      for (int ks = 0; ks < NKA; ++ks)                                         \
        yb[ks] = *(const half8*)(yrd[s][ks] + (RD));                           \
      _Pragma("unroll")                                                        \
      for (int k = 0; k < 2; ++k) {                                            \
        floatx4 a = {0.f, 0.f, 0.f, 0.f};                                      \
        _Pragma("unroll")                                                      \
        for (int ks = 0; ks < NKA; ++ks)                                       \
          a = MFMA16(GF[k][ks], yb[ks], a, 0, 0, 0);                           \
        half4 hv;                                                              \
        _Pragma("unroll")                                                      \
        for (int r = 0; r < 4; ++r) {                                          \
          const float w = yR[k][s][r] + fmaf(L_inv, a[r], Bc[k][s][r]);        \
          const float cl = fminf(fmaxf(w, -thr), thr);                         \
          const float xn = w - cl;                                             \
          const float yn = xn + ttf * (xn - xR[k][s][r]);                      \
          xR[k][s][r] = xn;                                                    \
          yR[k][s][r] = yn;                                                    \
          hv[r] = (half_t)yn;                                                  \
        }                                                                      \
        *(half4*)(ywr[k][s] + (WR)) = hv;                                      \
      }                                                                        \
    }                                                                          \
  } while (0)

  for (int it = 0; it < NITER; it += 2) {
    ITER_BODY(0, 24576, it);            // read buf0, write buf1
    __syncthreads();
    ITER_BODY(24576, 0, it + 1);        // read buf1, write buf0
    __syncthreads();
  }

  // ---- G. outputs: C = x_fin
  float* Cb = outC + b * PDIM * NCOL;
  #pragma unroll
  for (int k = 0; k < 2; ++k) {
    const int pt = g + 6 * k;
    #pragma unroll
    for (int s = 0; s < 2; ++s) {
      const int cS = 16 * (2 * h + s) + ln;
      if (cS < NCOL) {
        #pragma unroll
        for (int r = 0; r < 4; ++r) {
          const int p = 16 * pt + 4 * q + r;
          if (p < PDIM) Cb[p * NCOL + cS] = xR[k][s][r];
        }
      }
    }
  }
  // reconst = D @ C : stage x into buf0 (fp16), one hi-only GEMM from DAH
  #pragma unroll
  for (int k = 0; k < 2; ++k) {
    #pragma unroll
    for (int s = 0; s < 2; ++s) {
      half4 hv;
      #pragma unroll
      for (int r = 0; r < 4; ++r) hv[r] = (half_t)xR[k][s][r];
      *(half4*)(ywr[k][s]) = hv;
    }
  }
  __syncthreads();
  {
    const int mtA = wave >> 2, ntA = wave & 3;     // 3 mt x 4 nt
    const int rowD = 16 * mtA + ln;                // 0..47 (>=36 -> zero frag)
    const int n0 = 16 * ntA + ln;
    const half8 zz = {0, 0, 0, 0, 0, 0, 0, 0};
    floatx4 a = {0.f, 0.f, 0.f, 0.f};
    #pragma unroll
    for (int ks = 0; ks < NKA; ++ks) {
      const half8 dh_ = (rowD < TDIM)
        ? *(const half8*)(smc + BY_DAH + rowD * DROW + SWZ(rowD, (32 * ks + 8 * q) * 2))
        : zz;
      const half8 yb = *(const half8*)(smc + BY_Y + n0 * YROW + SWZ(n0, (32 * ks + 8 * q) * 2));
      a = MFMA16(dh_, yb, a, 0, 0, 0);
    }
    float* Rb = outR + b * TDIM * NCOL;
    if (n0 < NCOL) {
      const int t0 = 16 * mtA + 4 * q;
      #pragma unroll
      for (int r = 0; r < 4; ++r) {
        const int t = t0 + r;
        if (t < TDIM) Rb[t * NCOL + n0] = a[r];
      }
    }
  }
}

// ---------------- launch --------------------------------------------------------------

extern "C" void kernel_launch(void* const* d_in, const int* in_sizes, int n_in,
                              void* d_out, int out_size, void* d_ws, size_t ws_size,
                              hipStream_t stream) {
  const float* x     = (const float*)d_in[0];   // (256, 36, 50)
  const float* rho   = (const float*)d_in[1];   // (80,)
  const float* theta = (const float*)d_in[2];   // (80,)

  float* out    = (float*)d_out;
  float* outC   = out;                              // 256*161*50
  float* outDic = out + 256 * PDIM * NCOL;          // 36*161
  float* outR   = outDic + TDIM * PDIM;             // 256*36*50

  hipLaunchKernelGGL(dan_kernel, dim3(256), dim3(768), LDS_TOTAL, stream,
                     x, rho, theta, outC, outDic, outR);
}

// Round 16
// 212.026 us; speedup vs baseline: 1.2314x; 1.1854x over previous
//
#include <hip/hip_runtime.h>
#include <math.h>

typedef _Float16 half_t;
typedef __attribute__((ext_vector_type(8))) _Float16 half8;
typedef __attribute__((ext_vector_type(4))) _Float16 half4;
typedef __attribute__((ext_vector_type(4))) float floatx4;

#define TDIM 36
#define PDIM 161        // 2*80+1 atoms
#define NCOL 50
#define NITER 100
#define PITER8 50       // power steps on G^8 == 400 on G (proven config)

// R13 FINAL (best verified: 173.0 us kernel / 211.2 us bench, clean counters).
// R8 structure (768 thr, 12 waves, 3/SIMD) + VALU diet:
//  - ttf momentum table precomputed in setup (data-independent)
//  - loop-invariant swizzled LDS addresses hoisted to registers
// phase A: M=48,N=64,K=192 (6 ks), 12 waves = 3 mt x 4 nt, D hi/lo (12 MFMA)
// phase B: M=192 (12 pt incl ghost pt=11), N=64, K=64; wave (g=w>>1,h=w&1)
//          owns pt in {g,g+6}, stripes {2h,2h+1}; D^T hi ONLY -> 8 MFMA/wave.
// Eliminated alternatives (measured): multi-block desync (R2/R9/R10: spill or
// no co-residency), barrier-free 1-wave/SIMD (R12: 262 us latency-exposed),
// fused 1-barrier GEMM (R14/R15: allocator pins 84 VGPR and spills ~90 MB).
#define NKA 6
#define GSTR 44
#define SPS 196         // Df (fp32) row stride (dwords)

// row strides in BYTES
#define YROW 384        // y^T [64][192] half
#define RROW 128        // R^T [64][64] half

// XOR swizzle: spread same-column reads across 8 rows -> 8 distinct 16B slots
#define SWZ(row, byteoff) ((byteoff) ^ (((row) & 7) << 4))

// ---- byte-offset LDS map: 52,192 B ----
#define BY_Y    0                      // 24,576
#define BY_R    24576                  //  8,192
#define BY_LRTH 28672                  //  1,288 (inside R region, past Df end 28,224)
#define BY_SC   32768                  //     16
#define BY_TTF  32784                  //    400 (ttf[100] momentum table)
#define BY_GS   33184                  //  6,336
#define BY_G2   39520                  //  6,336  (holds G^2, later overwritten by G^8)
#define BY_G4   45856                  //  6,336
#define LDS_TOTAL 52192
// setup alias: Df fp32 [36][196] = 28,224 B over Y + head of R (re-zeroed pre-loop)

#define MFMA16 __builtin_amdgcn_mfma_f32_16x16x32_f16

__global__ __launch_bounds__(768, 3)
void dan_kernel(const float* __restrict__ xin, const float* __restrict__ rho,
                const float* __restrict__ theta, float* __restrict__ outC,
                float* __restrict__ outDic, float* __restrict__ outR)
{
  extern __shared__ char smc[];
  float*  sc   = (float*)(smc + BY_SC);
  float*  ttfT = (float*)(smc + BY_TTF);
  float*  Gs   = (float*)(smc + BY_GS);
  float*  G2   = (float*)(smc + BY_G2);
  float*  G4   = (float*)(smc + BY_G4);
  float*  Df   = (float*)(smc + BY_Y);    // setup alias
  float*  lrth = (float*)(smc + BY_LRTH); // [161] lr, [161] th (setup only)

  const int tid = threadIdx.x;
  const int b = blockIdx.x;
  const int wave = tid >> 6, lane = tid & 63;
  const int q = lane >> 4, ln = lane & 15;

  // ---- A. zero all LDS (pads must be 0)
  {
    unsigned int* z = (unsigned int*)smc;
    for (int i = tid; i < LDS_TOTAL / 4; i += 768) z[i] = 0u;
  }
  __syncthreads();

  // ---- B0. per-atom lr/th (161 threads, 2 transcendentals each)
  if (tid >= 1 && tid < PDIM) {
    const bool is_sin = tid > 80;
    const int n = is_sin ? (tid - 81) : (tid - 1);
    lrth[tid]       = logf(0.001f + 1.149f / (1.0f + expf(-rho[n])));
    lrth[161 + tid] = 3.14159265358979f / (1.0f + expf(-theta[n]));
  }
  __syncthreads();

  // ---- B1. raw dictionary, parallel over all (t,p) jobs
  for (int i = tid; i < TDIM * PDIM; i += 768) {
    const int t = i / PDIM, p = i - t * PDIM;
    float val;
    if (p == 0) {
      val = 1.0f;
    } else {
      const float ft = (float)t;
      const float e = expf(ft * lrth[p]);
      const float ang = ft * lrth[161 + p];
      val = e * (p > 80 ? sinf(ang) : cosf(ang));
    }
    Df[t * SPS + p] = val;
  }
  __syncthreads();

  // ---- B2. column-normalize (atoms 1..160)
  if (tid >= 1 && tid < PDIM) {
    float s2 = 0.0f;
    for (int t = 0; t < TDIM; ++t) {
      const float v = Df[t * SPS + tid];
      s2 += v * v;
    }
    const float inv = 1.0f / sqrtf(s2);
    for (int t = 0; t < TDIM; ++t) Df[t * SPS + tid] *= inv;
  }
  __syncthreads();

  // ---- C. Gram -> Gs ; dic out ; load ALL MFMA fragments to registers
  if (tid < 666) {                      // 666 = 36*37/2
    int i = 0, rem = tid;
    while (rem >= TDIM - i) { rem -= TDIM - i; ++i; }
    const int j = i + rem;
    const float4* ri = (const float4*)(Df + i * SPS);
    const float4* rj = (const float4*)(Df + j * SPS);
    float a = 0.0f;
    #pragma unroll 7
    for (int k = 0; k < SPS / 4; ++k) {
      const float4 x = ri[k], y = rj[k];
      a += x.x * y.x + x.y * y.y + x.z * y.z + x.w * y.w;
    }
    Gs[i * GSTR + j] = a;
    Gs[j * GSTR + i] = a;
  }
  if (b == 0) {
    for (int i = tid; i < TDIM * PDIM; i += 768) {
      const int t = i / PDIM, p = i - t * PDIM;
      outDic[i] = Df[t * SPS + p];
    }
  }

  // ownership maps
  const int mtA = wave >> 2;            // phase A: 3 mt x 4 nt, one tile per wave
  const int ntA = wave & 3;
  const int g = wave >> 1;              // phase B: pt in {g, g+6} (pt=11 = ghost)
  const int h = wave & 1;               //          stripes {2h, 2h+1}

  // phase-A A-fragments (D hi/lo); rows >= 36 are zero (Df region zero there)
  half8 DhF[NKA], DlF[NKA];
  {
    const int row = 16 * mtA + ln;
    #pragma unroll
    for (int ks = 0; ks < NKA; ++ks) {
      half8 hh = {0,0,0,0,0,0,0,0}, ll = {0,0,0,0,0,0,0,0};
      if (row < TDIM) {
        const float4 f0 = *(const float4*)(Df + row * SPS + 32 * ks + 8 * q);
        const float4 f1 = *(const float4*)(Df + row * SPS + 32 * ks + 8 * q + 4);
        const float fa[8] = {f0.x, f0.y, f0.z, f0.w, f1.x, f1.y, f1.z, f1.w};
        #pragma unroll
        for (int e = 0; e < 8; ++e) {
          const half_t h2 = (half_t)fa[e];
          hh[e] = h2;
          ll[e] = (half_t)(fa[e] - (float)h2);
        }
      }
      DhF[ks] = hh;
      DlF[ks] = ll;
    }
  }
  // phase-B A-fragments (D^T hi ONLY), transposed read from Df; atoms>=161 zero
  half8 DtH[2][2];                      // [k][ks]
  #pragma unroll
  for (int k = 0; k < 2; ++k) {
    const int atom = 16 * (g + 6 * k) + ln;         // 0..191 (>=161 -> zero cols)
    #pragma unroll
    for (int ks = 0; ks < 2; ++ks) {
      half8 hh;
      #pragma unroll
      for (int e = 0; e < 8; ++e) {
        const int t = 32 * ks + 8 * q + e;
        const float v = (t < TDIM) ? Df[t * SPS + atom] : 0.0f;
        hh[e] = (half_t)v;
      }
      DtH[k][ks] = hh;
    }
  }
  // static Y (fp32) at phase-A C positions
  float yA[4];
  {
    const float* xb = xin + b * TDIM * NCOL;
    const int c = 16 * ntA + ln;
    #pragma unroll
    for (int r = 0; r < 4; ++r) {
      const int t = 16 * mtA + 4 * q + r;
      yA[r] = (t < TDIM && c < NCOL) ? xb[t * NCOL + c] : 0.0f;
    }
  }
  __syncthreads();

  // ---- C2. G2 = G*G  (pads of all Gram buffers are zero)
  if (tid < 666) {
    int i = 0, rem = tid;
    while (rem >= TDIM - i) { rem -= TDIM - i; ++i; }
    const int j = i + rem;
    const float4* ri = (const float4*)(Gs + i * GSTR);
    const float4* rj = (const float4*)(Gs + j * GSTR);
    float a = 0.0f;
    #pragma unroll
    for (int k = 0; k < GSTR / 4; ++k) {
      const float4 x = ri[k], y = rj[k];
      a += x.x * y.x + x.y * y.y + x.z * y.z + x.w * y.w;
    }
    G2[i * GSTR + j] = a;
    G2[j * GSTR + i] = a;
  }
  __syncthreads();
  // ---- C3. G4 = G2*G2
  if (tid < 666) {
    int i = 0, rem = tid;
    while (rem >= TDIM - i) { rem -= TDIM - i; ++i; }
    const int j = i + rem;
    const float4* ri = (const float4*)(G2 + i * GSTR);
    const float4* rj = (const float4*)(G2 + j * GSTR);
    float a = 0.0f;
    #pragma unroll
    for (int k = 0; k < GSTR / 4; ++k) {
      const float4 x = ri[k], y = rj[k];
      a += x.x * y.x + x.y * y.y + x.z * y.z + x.w * y.w;
    }
    G4[i * GSTR + j] = a;
    G4[j * GSTR + i] = a;
  }
  __syncthreads();
  // ---- C4. G8 = G4*G4 -> overwrite G2 buffer
  if (tid < 666) {
    int i = 0, rem = tid;
    while (rem >= TDIM - i) { rem -= TDIM - i; ++i; }
    const int j = i + rem;
    const float4* ri = (const float4*)(G4 + i * GSTR);
    const float4* rj = (const float4*)(G4 + j * GSTR);
    float a = 0.0f;
    #pragma unroll
    for (int k = 0; k < GSTR / 4; ++k) {
      const float4 x = ri[k], y = rj[k];
      a += x.x * y.x + x.y * y.y + x.z * y.z + x.w * y.w;
    }
    G2[i * GSTR + j] = a;
    G2[j * GSTR + i] = a;
  }
  __syncthreads();

  // ---- D2. wave 0: power iteration on G8 ; others: zero Y+R ; tid64: ttf table
  if (wave == 0) {
    float g8r[36];
    #pragma unroll
    for (int j = 0; j < 36; ++j) g8r[j] = (lane < 36) ? G2[lane * GSTR + j] : 0.0f;
    float v = (lane < 36) ? 1.0f : 0.0f;
    for (int it = 0; it < PITER8; ++it) {
      const int vi = __float_as_int(v);
      float w0 = 0.0f, w1 = 0.0f, w2 = 0.0f, w3 = 0.0f;
      #pragma unroll
      for (int j = 0; j < 36; j += 4) {
        w0 = fmaf(g8r[j],     __int_as_float(__builtin_amdgcn_readlane(vi, j)),     w0);
        w1 = fmaf(g8r[j + 1], __int_as_float(__builtin_amdgcn_readlane(vi, j + 1)), w1);
        w2 = fmaf(g8r[j + 2], __int_as_float(__builtin_amdgcn_readlane(vi, j + 2)), w2);
        w3 = fmaf(g8r[j + 3], __int_as_float(__builtin_amdgcn_readlane(vi, j + 3)), w3);
      }
      float w = (w0 + w1) + (w2 + w3);
      float s = w * w;
      #pragma unroll
      for (int off = 32; off > 0; off >>= 1) s += __shfl_xor(s, off, 64);
      v = w * rsqrtf(s);
    }
    // Rayleigh on ORIGINAL G (v is unit)
    const int vi = __float_as_int(v);
    float w0 = 0.0f, w1 = 0.0f;
    #pragma unroll
    for (int j = 0; j < 36; j += 2) {
      const float gi0 = (lane < 36) ? Gs[lane * GSTR + j]     : 0.0f;
      const float gi1 = (lane < 36) ? Gs[lane * GSTR + j + 1] : 0.0f;
      w0 = fmaf(gi0, __int_as_float(__builtin_amdgcn_readlane(vi, j)),     w0);
      w1 = fmaf(gi1, __int_as_float(__builtin_amdgcn_readlane(vi, j + 1)), w1);
    }
    float num = v * (w0 + w1);
    #pragma unroll
    for (int off = 32; off > 0; off >>= 1) num += __shfl_xor(num, off, 64);
    if (lane == 0) {
      sc[0] = 1.0f / num;        // L_inv
      sc[1] = 0.1f / num;        // thr = lam_f * L_inv
    }
  } else {
    unsigned int* z = (unsigned int*)smc;
    for (int i = tid - 64; i < 32768 / 4; i += 704) z[i] = 0u;   // kill Df alias; y0=0
    if (tid == 64) {
      // data-independent momentum table; EXACT same f32 ops as the old in-loop code
      float t = 1.0f;
      for (int it = 0; it < NITER; ++it) {
        const float tn = 0.5f * (1.0f + sqrtf(1.0f + 4.0f * t * t));
        ttfT[it] = (t - 1.0f) / tn;
        t = tn;
      }
    }
  }
  __syncthreads();
  const float L_inv = sc[0];
  const float thr = sc[1];

  // ---- hoisted loop-invariant LDS addresses (15 pointers, unroll-const indexed)
  const int n0A = 16 * ntA + ln;
  const int t0A = 16 * mtA + 4 * q;
  const char* yrdA[NKA];
  #pragma unroll
  for (int ks = 0; ks < NKA; ++ks)
    yrdA[ks] = smc + BY_Y + n0A * YROW + SWZ(n0A, (32 * ks + 8 * q) * 2);
  char* rwrA = smc + BY_R + n0A * RROW + SWZ(n0A, t0A * 2);

  const char* rrdB[2][2];               // [s][ks]
  char* ywrB[2][2];                     // [k][s]
  #pragma unroll
  for (int s = 0; s < 2; ++s) {
    const int cS = 16 * (2 * h + s) + ln;
    rrdB[s][0] = smc + BY_R + cS * RROW + SWZ(cS, 16 * q);
    rrdB[s][1] = smc + BY_R + cS * RROW + SWZ(cS, 64 + 16 * q);
    #pragma unroll
    for (int k = 0; k < 2; ++k) {
      const int p0 = 16 * (g + 6 * k) + 4 * q;
      ywrB[k][s] = smc + BY_Y + cS * YROW + SWZ(cS, p0 * 2);
    }
  }

  float xR[2][2][4], yR[2][2][4];       // [pt-idx][stripe][r]
  #pragma unroll
  for (int k = 0; k < 2; ++k)
    #pragma unroll
    for (int s = 0; s < 2; ++s)
      #pragma unroll
      for (int r = 0; r < 4; ++r) { xR[k][s][r] = 0.0f; yR[k][s][r] = 0.0f; }

  // ---- F. FISTA loop (R8 body; ttf from table; addresses precomputed)
  for (int it = 0; it < NITER; ++it) {
    // phase A (all 12 waves): R = Y - D y   (M=48, N=64, K=192)
    {
      floatx4 aH0 = {0.f,0.f,0.f,0.f}, aH1 = {0.f,0.f,0.f,0.f};
      floatx4 aL0 = {0.f,0.f,0.f,0.f}, aL1 = {0.f,0.f,0.f,0.f};
      #pragma unroll
      for (int ks = 0; ks < NKA; ++ks) {
        const half8 b0 = *(const half8*)(yrdA[ks]);
        if (ks & 1) {
          aH1 = MFMA16(DhF[ks], b0, aH1, 0, 0, 0);
          aL1 = MFMA16(DlF[ks], b0, aL1, 0, 0, 0);
        } else {
          aH0 = MFMA16(DhF[ks], b0, aH0, 0, 0, 0);
          aL0 = MFMA16(DlF[ks], b0, aL0, 0, 0, 0);
        }
      }
      half4 hv;
      #pragma unroll
      for (int r = 0; r < 4; ++r)
        hv[r] = (half_t)(yA[r] - ((aH0[r] + aH1[r]) + (aL0[r] + aL1[r])));
      *(half4*)rwrA = hv;
    }
    __syncthreads();

    const float ttf = ttfT[it];

    // phase B: w = y + L_inv D^T R ; shrink + momentum  (hi-only D^T)
    {
      half8 rb[2][2];
      #pragma unroll
      for (int s = 0; s < 2; ++s) {
        rb[s][0] = *(const half8*)(rrdB[s][0]);
        rb[s][1] = *(const half8*)(rrdB[s][1]);
      }

      #pragma unroll
      for (int k = 0; k < 2; ++k) {
        #pragma unroll
        for (int s = 0; s < 2; ++s) {
          floatx4 a = {0.f,0.f,0.f,0.f};
          a = MFMA16(DtH[k][0], rb[s][0], a, 0, 0, 0);
          a = MFMA16(DtH[k][1], rb[s][1], a, 0, 0, 0);
          half4 hv;
          #pragma unroll
          for (int r = 0; r < 4; ++r) {
            const float w = yR[k][s][r] + L_inv * a[r];
            const float cl = fminf(fmaxf(w, -thr), thr);   // v_med3 clamp
            const float xn = w - cl;                        // softshrink
            const float yn = xn + ttf * (xn - xR[k][s][r]);
            xR[k][s][r] = xn;
            yR[k][s][r] = yn;
            hv[r] = (half_t)yn;
          }
          *(half4*)(ywrB[k][s]) = hv;
        }
      }
    }
    __syncthreads();
  }

  // ---- G. outputs: C = x_fin (ghost pt=11 masked by p<PDIM)
  float* Cb = outC + b * PDIM * NCOL;
  #pragma unroll
  for (int k = 0; k < 2; ++k) {
    const int pt = g + 6 * k;
    #pragma unroll
    for (int s = 0; s < 2; ++s) {
      const int cS = 16 * (2 * h + s) + ln;
      if (cS < NCOL) {
        #pragma unroll
        for (int r = 0; r < 4; ++r) {
          const int p = 16 * pt + 4 * q + r;
          if (p < PDIM) Cb[p * NCOL + cS] = xR[k][s][r];
        }
      }
    }
  }
  // reconst = D @ C : restage x into Y (fp16), rerun phase-A GEMM
  #pragma unroll
  for (int k = 0; k < 2; ++k) {
    #pragma unroll
    for (int s = 0; s < 2; ++s) {
      half4 hv;
      #pragma unroll
      for (int r = 0; r < 4; ++r) hv[r] = (half_t)xR[k][s][r];
      *(half4*)(ywrB[k][s]) = hv;
    }
  }
  __syncthreads();
  {
    floatx4 aH0 = {0.f,0.f,0.f,0.f}, aH1 = {0.f,0.f,0.f,0.f};
    floatx4 aL0 = {0.f,0.f,0.f,0.f}, aL1 = {0.f,0.f,0.f,0.f};
    #pragma unroll
    for (int ks = 0; ks < NKA; ++ks) {
      const half8 b0 = *(const half8*)(yrdA[ks]);
      if (ks & 1) {
        aH1 = MFMA16(DhF[ks], b0, aH1, 0, 0, 0);
        aL1 = MFMA16(DlF[ks], b0, aL1, 0, 0, 0);
      } else {
        aH0 = MFMA16(DhF[ks], b0, aH0, 0, 0, 0);
        aL0 = MFMA16(DlF[ks], b0, aL0, 0, 0, 0);
      }
    }
    float* Rb = outR + b * TDIM * NCOL;
    const int c = n0A;
    if (c < NCOL) {
      #pragma unroll
      for (int r = 0; r < 4; ++r) {
        const int t = t0A + r;
        if (t < TDIM)
          Rb[t * NCOL + c] = (aH0[r] + aH1[r]) + (aL0[r] + aL1[r]);
      }
    }
  }
}

// ---------------- launch --------------------------------------------------------------

extern "C" void kernel_launch(void* const* d_in, const int* in_sizes, int n_in,
                              void* d_out, int out_size, void* d_ws, size_t ws_size,
                              hipStream_t stream) {
  const float* x     = (const float*)d_in[0];   // (256, 36, 50)
  const float* rho   = (const float*)d_in[1];   // (80,)
  const float* theta = (const float*)d_in[2];   // (80,)

  float* out    = (float*)d_out;
  float* outC   = out;                              // 256*161*50
  float* outDic = out + 256 * PDIM * NCOL;          // 36*161
  float* outR   = outDic + TDIM * PDIM;             // 256*36*50

  hipLaunchKernelGGL(dan_kernel, dim3(256), dim3(768), LDS_TOTAL, stream,
                     x, rho, theta, outC, outDic, outR);
}